// Round 4
// baseline (309.022 us; speedup 1.0000x reference)
//
#include <hip/hip_runtime.h>
#include <hip/hip_bf16.h>
#include <math.h>
#include <stdint.h>

#define L_      4096
#define D_      2048
#define H_      8
#define KVH_    2
#define HD_     256
#define WINDOW_ 512
#define QKVW    3072   // 2048 q + 512 k + 512 v

typedef __attribute__((ext_vector_type(8))) _Float16 f16x8;
typedef __attribute__((ext_vector_type(4))) _Float16 f16x4;
typedef __attribute__((ext_vector_type(4))) short s16x4;
typedef __attribute__((ext_vector_type(4))) float f32x4;

__device__ __forceinline__ short f2h(float f) {
    _Float16 h = (_Float16)f;           // RNE
    return *reinterpret_cast<short*>(&h);
}
__device__ __forceinline__ float h2f(short s) {
    _Float16 h = *reinterpret_cast<_Float16*>(&s);
    return (float)h;
}

// async global->LDS 16B per lane; lds base must be wave-uniform
__device__ __forceinline__ void gl2lds16(const void* g, void* l) {
    __builtin_amdgcn_global_load_lds(
        (const __attribute__((address_space(1))) uint32_t*)g,
        (__attribute__((address_space(3))) uint32_t*)l, 16, 0, 0);
}

// ---------------------------------------------------------------------------
// cast fp32 -> fp16 (bits in short), 8 elems/thread
// ---------------------------------------------------------------------------
__global__ __launch_bounds__(256) void cast_f16(const float* __restrict__ X,
                                                short* __restrict__ Y, int n) {
    int idx = (blockIdx.x * 256 + threadIdx.x) * 8;
    if (idx >= n) return;
    float4 a = *(const float4*)(X + idx);
    float4 b = *(const float4*)(X + idx + 4);
    s16x4 o0, o1;
    o0[0]=f2h(a.x); o0[1]=f2h(a.y); o0[2]=f2h(a.z); o0[3]=f2h(a.w);
    o1[0]=f2h(b.x); o1[1]=f2h(b.y); o1[2]=f2h(b.z); o1[3]=f2h(b.w);
    *(s16x4*)(Y + idx)     = o0;
    *(s16x4*)(Y + idx + 4) = o1;
}

// ---------------------------------------------------------------------------
// transpose-cast: W fp32 [K][N] -> Wt fp16 [N][K]
// ---------------------------------------------------------------------------
__global__ __launch_bounds__(256) void transpose_cast(const float* __restrict__ W,
                                                      short* __restrict__ Wt,
                                                      int K, int N) {
    __shared__ float tl[32][33];
    int t = threadIdx.x;
    int c = t & 31, r4 = (t >> 5) * 4;
    int k0 = blockIdx.y * 32, n0 = blockIdx.x * 32;
#pragma unroll
    for (int i = 0; i < 4; ++i)
        tl[r4 + i][c] = W[(size_t)(k0 + r4 + i) * N + n0 + c];
    __syncthreads();
#pragma unroll
    for (int i = 0; i < 4; ++i)
        Wt[(size_t)(n0 + r4 + i) * K + k0 + c] = f2h(tl[c][r4 + i]);
}

// ---------------------------------------------------------------------------
// fp16 MFMA GEMM v2 (output projection): 128x128 tile, BK=64, XOR-swizzled.
// ---------------------------------------------------------------------------
template <int OUT_HALF>
__global__ __launch_bounds__(256) void gemm_mfma(const short* __restrict__ A,
                                                 const short* __restrict__ Bt,
                                                 void* __restrict__ Cout,
                                                 int M, int N, int K) {
    __shared__ short As[128][64];   // 16 KB each, rows 128B
    __shared__ short Bs[128][64];

    const int tid = threadIdx.x;
    const int w = tid >> 6, lane = tid & 63;
    const int lq = lane & 15, quad = lane >> 4;
    const int bm = blockIdx.y * 128, bn = blockIdx.x * 128;
    const int wm = (w & 1) * 64, wn = (w >> 1) * 64;
    const int lrow = lane >> 3;      // 0..7: row within 8-row staging group
    const int slot = lane & 7;       // 0..7: LDS 16B slot this lane fills

    f32x4 acc[4][4];
#pragma unroll
    for (int i = 0; i < 4; ++i)
#pragma unroll
        for (int j = 0; j < 4; ++j) acc[i][j] = 0;

    for (int k0 = 0; k0 < K; k0 += 64) {
        // stage 128 rows x 128B per matrix; wave stages 8 rows per instr
#pragma unroll
        for (int c = 0; c < 4; ++c) {
            const int r0 = w * 32 + c * 8;            // wave-uniform
            const int row = r0 + lrow;
            const int chunk = slot ^ (row & 7);       // swizzled source chunk
            gl2lds16(A  + (size_t)(bm + row) * K + k0 + chunk * 8, &As[r0][0]);
            gl2lds16(Bt + (size_t)(bn + row) * K + k0 + chunk * 8, &Bs[r0][0]);
        }
        __syncthreads();   // drains vmcnt -> staged data visible

#pragma unroll
        for (int f = 0; f < 2; ++f) {
            const int sA = (((f * 4) + quad) ^ (lq & 7)) * 8;  // un-swizzle
            f16x8 af[4], bfr[4];
#pragma unroll
            for (int i = 0; i < 4; ++i) af[i]  = *(const f16x8*)&As[wm + i * 16 + lq][sA];
#pragma unroll
            for (int j = 0; j < 4; ++j) bfr[j] = *(const f16x8*)&Bs[wn + j * 16 + lq][sA];
#pragma unroll
            for (int i = 0; i < 4; ++i)
#pragma unroll
                for (int j = 0; j < 4; ++j)
                    acc[i][j] = __builtin_amdgcn_mfma_f32_16x16x32_f16(af[i], bfr[j], acc[i][j], 0, 0, 0);
        }
        __syncthreads();
    }

    // epilogue: C/D layout col=lane&15, row=quad*4+reg
#pragma unroll
    for (int i = 0; i < 4; ++i)
#pragma unroll
        for (int r = 0; r < 4; ++r) {
            int row = bm + wm + i * 16 + quad * 4 + r;
#pragma unroll
            for (int j = 0; j < 4; ++j) {
                int col = bn + wn + j * 16 + lq;
                float v = acc[i][j][r];
                if (OUT_HALF) ((short*)Cout)[(size_t)row * N + col] = f2h(v);
                else          ((float*)Cout)[(size_t)row * N + col] = v;
            }
        }
}

// ---------------------------------------------------------------------------
// fp16 MFMA GEMM v3.1 — 256x256 tile, BK=64, 512 threads (8 waves, 2Mx4N),
// 8-phase counted-vmcnt schedule (T2+T3+T4+T5), register-resident B.
// Per-phase reads (slot S): ph1 af(mq0)[8]+bfA[4]=12, ph2 bfB[4],
// ph3 af(mq1)[8], ph4 none -> 24 ds_read_b128 / K-tile / wave (m201 parity).
// Stage schedule & per-phase vmcnt(6) ledger identical to the verified R1
// version: every stage lands >=4 phases before its first read; every stage
// write targets a region last read >=2 barriers earlier. Tail clamps source
// addresses (garbage into never-read slots keeps vmcnt bookkeeping exact).
// ---------------------------------------------------------------------------
template <int OUT_HALF>
__global__ __launch_bounds__(512, 2) void gemm_mfma256(const short* __restrict__ A,
                                                       const short* __restrict__ Bt,
                                                       void* __restrict__ Cout,
                                                       int M, int N, int K) {
    __shared__ short As[2][256][64];   // 64 KB
    __shared__ short Bs[2][256][64];   // 64 KB

    const int tid = threadIdx.x;
    const int w = tid >> 6, lane = tid & 63;
    const int lq = lane & 15, quad = lane >> 4;
    const int lq7 = lq & 7;
    const int wm128 = (w >> 2) * 128;      // 2 M wave-groups
    const int wn = (w & 3) * 64;           // 4 N wave-groups

    // bijective XCD-chunked swizzle (grid count % 8 == 0 for our launches)
    int bid = blockIdx.y * gridDim.x + blockIdx.x;
    int nwg = gridDim.x * gridDim.y;
    int qch = nwg >> 3;
    int swz = (bid & 7) * qch + (bid >> 3);
    const int bn = (swz % gridDim.x) * 256;
    const int bm = (swz / gridDim.x) * 256;

    const int KT = K >> 6, KTm1 = KT - 1;

    // stage one A half-tile (rows i*128 + mq*64 + 0..63) of k-tile kt2 into slot s
    auto stageA = [&](int s, int kt2, int mq) {
        const int k0 = min(kt2, KTm1) * 64;
#pragma unroll
        for (int i = 0; i < 2; ++i) {
            const int r0 = i * 128 + mq * 64 + w * 8;      // wave-uniform
            const int row = r0 + (lane >> 3);
            const int chunk = (lane & 7) ^ (row & 7);
            gl2lds16(A + (size_t)(bm + row) * K + k0 + chunk * 8, &As[s][r0][0]);
        }
    };
    // stage one B half-tile (rows 64g + nq*32 + 0..31, g=0..3) into slot s
    auto stageB = [&](int s, int kt2, int nq) {
        const int k0 = min(kt2, KTm1) * 64;
#pragma unroll
        for (int i = 0; i < 2; ++i) {
            const int g = i * 2 + (w >> 2);
            const int r0 = g * 64 + nq * 32 + (w & 3) * 8; // wave-uniform
            const int row = r0 + (lane >> 3);
            const int chunk = (lane & 7) ^ (row & 7);
            gl2lds16(Bt + (size_t)(bn + row) * K + k0 + chunk * 8, &Bs[s][r0][0]);
        }
    };

    f32x4 acc[8][4];
#pragma unroll
    for (int i = 0; i < 8; ++i)
#pragma unroll
        for (int j = 0; j < 4; ++j) acc[i][j] = 0;

    f16x8 af[4][2];      // A-frags of current mq (reused across the 2 nq phases)
    f16x8 bf[2][2][2];   // [nq][j][ks] — BOTH B-quadrants resident per K-tile

#define QPHASE(S, MQ, NQ, READA, READB, STAGE_STMT)                              \
    do {                                                                         \
        if (READA) {                                                             \
            _Pragma("unroll") for (int i_ = 0; i_ < 4; ++i_)                     \
            _Pragma("unroll") for (int ks_ = 0; ks_ < 2; ++ks_)                  \
                af[i_][ks_] = *(const f16x8*)&As[S][wm128 + (MQ)*64 + i_*16 + lq]\
                                                   [((ks_*4 + quad) ^ lq7) * 8]; \
        }                                                                        \
        if (READB) {                                                             \
            _Pragma("unroll") for (int j_ = 0; j_ < 2; ++j_)                     \
            _Pragma("unroll") for (int ks_ = 0; ks_ < 2; ++ks_)                  \
                bf[NQ][j_][ks_] = *(const f16x8*)&Bs[S][wn + (NQ)*32 + j_*16 + lq]\
                                                     [((ks_*4 + quad) ^ lq7) * 8]; \
        }                                                                        \
        STAGE_STMT;                                                              \
        asm volatile("s_waitcnt vmcnt(6)" ::: "memory");                         \
        __builtin_amdgcn_s_barrier();                                            \
        asm volatile("s_waitcnt lgkmcnt(0)" ::: "memory");                       \
        __builtin_amdgcn_sched_barrier(0);                                       \
        __builtin_amdgcn_s_setprio(1);                                           \
        _Pragma("unroll") for (int i_ = 0; i_ < 4; ++i_)                         \
        _Pragma("unroll") for (int j_ = 0; j_ < 2; ++j_) {                       \
            acc[(MQ)*4 + i_][(NQ)*2 + j_] = __builtin_amdgcn_mfma_f32_16x16x32_f16( \
                af[i_][0], bf[NQ][j_][0], acc[(MQ)*4 + i_][(NQ)*2 + j_], 0, 0, 0);  \
            acc[(MQ)*4 + i_][(NQ)*2 + j_] = __builtin_amdgcn_mfma_f32_16x16x32_f16( \
                af[i_][1], bf[NQ][j_][1], acc[(MQ)*4 + i_][(NQ)*2 + j_], 0, 0, 0);  \
        }                                                                        \
        __builtin_amdgcn_s_setprio(0);                                           \
        __builtin_amdgcn_s_barrier();                                            \
    } while (0)

    // prologue: 5 half-tile stages (#1..#5), then guarantee #1,#2 landed
    stageA(0, 0, 0);   // #1 tile0 A-h0
    stageB(0, 0, 0);   // #2 tile0 B-h0
    stageB(0, 0, 1);   // #3 tile0 B-h1
    stageA(0, 0, 1);   // #4 tile0 A-h1
    stageA(1, 1, 0);   // #5 tile1 A-h0
    asm volatile("s_waitcnt vmcnt(6)" ::: "memory");
    __builtin_amdgcn_s_barrier();

    for (int kt = 0; kt < KT; kt += 2) {
        // tile kt (slot 0)
        QPHASE(0, 0, 0, 1, 1, stageB(1, kt + 1, 0));
        QPHASE(0, 0, 1, 0, 1, stageB(1, kt + 1, 1));
        QPHASE(0, 1, 0, 1, 0, stageA(1, kt + 1, 1));
        QPHASE(0, 1, 1, 0, 0, stageA(0, kt + 2, 0));
        // tile kt+1 (slot 1)
        QPHASE(1, 0, 0, 1, 1, stageB(0, kt + 2, 0));
        QPHASE(1, 0, 1, 0, 1, stageB(0, kt + 2, 1));
        QPHASE(1, 1, 0, 1, 0, stageA(0, kt + 2, 1));
        QPHASE(1, 1, 1, 0, 0, stageA(1, kt + 3, 0));
    }
#undef QPHASE

    // drain the tail's clamped garbage stages before the block exits
    asm volatile("s_waitcnt vmcnt(0)" ::: "memory");

    // epilogue: C/D layout col=lane&15, row=quad*4+reg
#pragma unroll
    for (int mi = 0; mi < 8; ++mi)
#pragma unroll
        for (int r = 0; r < 4; ++r) {
            int row = bm + wm128 + mi * 16 + quad * 4 + r;
#pragma unroll
            for (int j = 0; j < 4; ++j) {
                int col = bn + wn + j * 16 + lq;
                float v = acc[mi][j][r];
                if (OUT_HALF) ((short*)Cout)[(size_t)row * N + col] = f2h(v);
                else          ((float*)Cout)[(size_t)row * N + col] = v;
            }
        }
}

// ---------------------------------------------------------------------------
// RMSNorm (+scale) (+RoPE), wave-per-row, no LDS/barriers.
// ---------------------------------------------------------------------------
__global__ __launch_bounds__(256) void norm_rope_w(short* __restrict__ qkv,
                                                   const float* __restrict__ q_scale,
                                                   const float* __restrict__ k_scale,
                                                   const int* __restrict__ positions) {
    const int w = threadIdx.x >> 6, lane = threadIdx.x & 63;
    const int row = blockIdx.x * 4 + w;
    const int token = row / 12, ridx = row % 12;
    short* p = qkv + (size_t)token * QKVW + ridx * HD_ + lane * 4;

    const s16x4 raw = *(const s16x4*)p;
    float xv[4];
#pragma unroll
    for (int i = 0; i < 4; ++i) xv[i] = h2f(raw[i]);
    float ss = xv[0]*xv[0] + xv[1]*xv[1] + xv[2]*xv[2] + xv[3]*xv[3];
#pragma unroll
    for (int off = 32; off > 0; off >>= 1) ss += __shfl_xor(ss, off);
    const float rinv = rsqrtf(ss * (1.0f / (float)HD_) + 1e-6f);
#pragma unroll
    for (int i = 0; i < 4; ++i) xv[i] *= rinv;

    if (ridx < 10) {                                  // q,k: scale + rope
        const float* scp = (ridx < 8 ? q_scale : k_scale) + lane * 4;
        const float4 sc = *(const float4*)scp;
        xv[0] *= sc.x; xv[1] *= sc.y; xv[2] *= sc.z; xv[3] *= sc.w;

        const int pos = positions[token];
        float ov[4];
#pragma unroll
        for (int i = 0; i < 4; ++i) ov[i] = __shfl_xor(xv[i], 32);
        const float sgn = (lane < 32) ? -1.0f : 1.0f;
        const int dbase = (lane & 31) * 4;            // freq index base
#pragma unroll
        for (int i = 0; i < 4; ++i) {
            const float fe = (float)(dbase + i) * (1.0f / 128.0f);
            const float inv_ts = __expf(fe * -9.210340371976184f);   // BASE^-fe
            const float ang = (float)pos * inv_ts;
            float s, c;
            __sincosf(ang, &s, &c);
            xv[i] = xv[i] * c + sgn * ov[i] * s;
        }
    }

    s16x4 o;
#pragma unroll
    for (int i = 0; i < 4; ++i) o[i] = f2h(xv[i]);
    *(s16x4*)p = o;
}

// ---------------------------------------------------------------------------
// V transpose: normalized V from qkv -> Vt_glob[g][d][L] (fp16)
// ---------------------------------------------------------------------------
__global__ __launch_bounds__(256) void vt_prep(const short* __restrict__ qkv,
                                               short* __restrict__ vtg) {
    const int tok0 = blockIdx.x * 64;
    const int g = blockIdx.y;
    const int tid = threadIdx.x;
    __shared__ short Vs[64][264];
#pragma unroll
    for (int i = 0; i < 8; ++i) {
        int f = (tid + i * 256) * 8;
        int tok = f >> 8, d = f & 255;
        *(int4*)&Vs[tok][d] =
            *(const int4*)(qkv + (size_t)(tok0 + tok) * QKVW + 2560 + g * HD_ + d);
    }
    __syncthreads();
    const int d = tid;
    short tmp[64];
#pragma unroll
    for (int j = 0; j < 64; ++j) tmp[j] = Vs[j][d];
    short* dst = vtg + ((size_t)g * HD_ + d) * L_ + tok0;
#pragma unroll
    for (int c = 0; c < 8; ++c)
        *(int4*)(dst + c * 8) = *(const int4*)&tmp[c * 8];
}

// ---------------------------------------------------------------------------
// Flash MFMA attention v4 — S^T layout, global_load_lds staging, double
// buffer, counted vmcnt(8), raw s_barrier.
// ---------------------------------------------------------------------------
__global__ __launch_bounds__(256) void attn_mfma(const short* __restrict__ qkv,
                                                 const short* __restrict__ vtg,
                                                 short* __restrict__ ao) {
    const int bx = blockIdx.x;
    const int g = bx & 1, qt = bx >> 1;
    const int q0 = qt * 16;
    const int tid = threadIdx.x;
    const int w = tid >> 6, lane = tid & 63;
    const int lq = lane & 15, quad = lane >> 4;
    const int h = g * 4 + w;

    // [0,16384): Ks[2][32][256]  [16384,32768): Vt[2][16][512]
    __shared__ short lds[32768];   // 64 KiB

    // Q B-fragments: B[k=quad*8+j][n=lq] = Q[q0+lq][f*32+quad*8]
    f16x8 qf[8];
    {
        const short* qrow = qkv + (size_t)(q0 + lq) * QKVW + h * HD_;
#pragma unroll
        for (int f = 0; f < 8; ++f)
            qf[f] = *(const f16x8*)(qrow + f * 32 + quad * 8);
    }

    float m_run = -INFINITY, l_run = 0.0f;   // per-lane: query q0+lq

    f32x4 accO[16];                          // O^T[d=dt*16+quad*4+r][q=lq]
#pragma unroll
    for (int dt = 0; dt < 16; ++dt) accO[dt] = 0;

    const short* kcol = qkv + 2048 + g * HD_;
    const short* vrow = vtg + (size_t)g * HD_ * L_;
    const int qi = q0 + lq;

    // staging lane roles
    const int kl5 = lane >> 5;               // K: row within pair
    const int ksl = lane & 31;               // K: 16B slot
    const int vdm = ((lane >> 5) << 3) | (lane & 7);   // V: d within window
    const int vkc = (lane >> 3) & 3;                   // V: 8-key chunk

    auto stageKV = [&](int b, int kb) {
#pragma unroll
        for (int i = 0; i < 4; ++i) {
            const int r0 = w * 8 + 2 * i;                  // wave-uniform
            const int row = r0 + kl5;
            const int cs = ksl ^ (row & 7);                // swizzled src chunk
            const int kj = min(max(kb + row, 0), L_ - 1);  // masked later
            gl2lds16(kcol + (size_t)kj * QKVW + cs * 8, lds + b * 8192 + r0 * 256);
        }
        const int ck = min(max(kb + vkc * 8, 0), L_ - 8);
#pragma unroll
        for (int j = 0; j < 4; ++j) {
            const int wv = w * 4 + j;                      // wave-uniform
            gl2lds16(vrow + (size_t)(wv * 16 + vdm) * L_ + ck,
                     lds + 16384 + b * 8192 + wv * 512);
        }
    };

    // first tile with any valid key: kbase+32 > 0
    const int kt0 = (q0 >= 480) ? 0 : ((480 - q0) / 32 + 1);
    int buf = 0;
    stageKV(0, q0 - WINDOW_ + kt0 * 32);

    for (int kt = kt0; kt < 17; ++kt) {
        const int kbase = q0 - WINDOW_ + kt * 32;
        if (kt < 16) {
            stageKV(buf ^ 1, kbase + 32);
            asm volatile("s_waitcnt vmcnt(8)" ::: "memory");   // tile kt landed
        } else {
            asm volatile("s_waitcnt vmcnt(0)" ::: "memory");
        }
        __builtin_amdgcn_s_barrier();
        __builtin_amdgcn_sched_barrier(0);

        const short* KsB = lds + buf * 8192;
        const short* VtB = lds + 16384 + buf * 8192;

        // --- S^T = K Q^T : two 16-key subtiles ---
        f32x4 st0 = 0, st1 = 0;
        __builtin_amdgcn_s_setprio(1);
#pragma unroll
        for (int f = 0; f < 8; ++f) {
            const int sl = ((f * 4 + quad) ^ (lq & 7)) * 8;
            f16x8 kf0 = *(const f16x8*)(KsB + lq * 256 + sl);
            f16x8 kf1 = *(const f16x8*)(KsB + (16 + lq) * 256 + sl);
            st0 = __builtin_amdgcn_mfma_f32_16x16x32_f16(kf0, qf[f], st0, 0, 0, 0);
            st1 = __builtin_amdgcn_mfma_f32_16x16x32_f16(kf1, qf[f], st1, 0, 0, 0);
        }
        __builtin_amdgcn_s_setprio(0);

        // --- register softmax (keys on (quad,r), query = lq) ---
        const int kA = kbase + quad * 4;
        const int kB = kA + 16;
        float sv[8]; bool vd[8];
#pragma unroll
        for (int r = 0; r < 4; ++r) {
            int ka = kA + r, kb2 = kB + r;
            vd[r]     = (ka >= 0) && (ka <= qi) && (ka > qi - WINDOW_);
            vd[4 + r] = (kb2 >= 0) && (kb2 <= qi) && (kb2 > qi - WINDOW_);
            sv[r]     = vd[r]     ? st0[r] : -INFINITY;
            sv[4 + r] = vd[4 + r] ? st1[r] : -INFINITY;
        }
        float mt = sv[0];
#pragma unroll
        for (int i = 1; i < 8; ++i) mt = fmaxf(mt, sv[i]);
        mt = fmaxf(mt, __shfl_xor(mt, 16));
        mt = fmaxf(mt, __shfl_xor(mt, 32));
        const float mn = fmaxf(m_run, mt);
        const float alpha = (mn == -INFINITY) ? 1.0f : __expf(m_run - mn);
        float pv[8], rs = 0.0f;
#pragma unroll
        for (int i = 0; i < 8; ++i) {
            pv[i] = vd[i] ? __expf(sv[i] - mn) : 0.0f;
            rs += pv[i];
        }
        rs += __shfl_xor(rs, 16);
        rs += __shfl_xor(rs, 32);
        m_run = mn;
        l_run = l_run * alpha + rs;

        // P^T B-frags (B[k=quad*4+i][n=lq]) straight from registers
        f16x4 p0, p1;
#pragma unroll
        for (int i = 0; i < 4; ++i) { p0[i] = (_Float16)pv[i]; p1[i] = (_Float16)pv[4 + i]; }

        // --- PV: O^T[d][q] += V^T[d][k] P^T[k][q], 16x16x16 MFMAs ---
        const int sl0 = ((lq >> 3) << 5) | ((quad >> 1) << 3) | (lq & 7);
        const int hh = (quad & 1) * 4;
        __builtin_amdgcn_s_setprio(1);
#pragma unroll
        for (int dt = 0; dt < 16; ++dt) {
            f16x4 v0 = *(const f16x4*)(VtB + dt * 512 + sl0 * 8 + hh);
            f16x4 v1 = *(const f16x4*)(VtB + dt * 512 + (sl0 | 16) * 8 + hh);
            f32x4 t = accO[dt];
#pragma unroll
            for (int r = 0; r < 4; ++r) t[r] *= alpha;
            t = __builtin_amdgcn_mfma_f32_16x16x16f16(v0, p0, t, 0, 0, 0);
            t = __builtin_amdgcn_mfma_f32_16x16x16f16(v1, p1, t, 0, 0, 0);
            accO[dt] = t;
        }
        __builtin_amdgcn_s_setprio(0);

        __builtin_amdgcn_s_barrier();     // all reads of buf done before restage
        __builtin_amdgcn_sched_barrier(0);
        buf ^= 1;
    }

    // --- epilogue: untranspose O^T via per-wave LDS region, then coalesced store
    const float inv = 1.0f / l_run;            // per-query (lane) scalar
    short* myE = lds + w * 4224;               // 16 rows x 264 shorts per wave
#pragma unroll
    for (int dt = 0; dt < 16; ++dt) {
        f16x4 e;
#pragma unroll
        for (int r = 0; r < 4; ++r) e[r] = (_Float16)(accO[dt][r] * inv);
        *(f16x4*)&myE[lq * 264 + dt * 16 + quad * 4] = e;   // O[q=lq][d]
    }
    // same-wave read-back (lgkmcnt only), coalesced global store
    {
        const int row = lane >> 2;             // 16 q rows
        const int c0 = (lane & 3) * 64;        // 4 x 64-short segments
        short* orow = ao + (size_t)(q0 + row) * 2048 + h * HD_ + c0;
#pragma unroll
        for (int u = 0; u < 8; ++u)
            *(int4*)(orow + u * 8) = *(const int4*)&myE[row * 264 + c0 + u * 8];
    }
}

// ---------------------------------------------------------------------------
extern "C" void kernel_launch(void* const* d_in, const int* in_sizes, int n_in,
                              void* d_out, int out_size, void* d_ws, size_t ws_size,
                              hipStream_t stream) {
    const float* x         = (const float*)d_in[0];
    const int*   positions = (const int*)d_in[1];
    const float* Wq        = (const float*)d_in[2];
    const float* Wk        = (const float*)d_in[3];
    const float* Wv        = (const float*)d_in[4];
    const float* Wo        = (const float*)d_in[5];
    const float* q_scale   = (const float*)d_in[6];
    const float* k_scale   = (const float*)d_in[7];
    float*       out       = (float*)d_out;

    // workspace layout (bytes, ~80 MB total)
    char* ws = (char*)d_ws;
    short* xb    = (short*)(ws);                 // [4096][2048] f16   16 MB
    short* qkv   = (short*)(ws + 16777216);      // [4096][3072] f16   24 MB
    short* ao    = (short*)(ws + 41943040);      // [4096][2048] f16   16 MB
    short* Wtqkv = (short*)(ws + 58720256);      // [3072][2048] f16   12 MB
    short* Wto   = (short*)(ws + 71303168);      // [2048][2048] f16    8 MB
    short* vtg   = xb;                           // aliases xb (dead after QKV GEMM)

    // 1) casts + weight transposes
    cast_f16<<<4096, 256, 0, stream>>>(x, xb, L_ * D_);
    transpose_cast<<<dim3(2048 / 32, 2048 / 32), 256, 0, stream>>>(Wq, Wtqkv, D_, 2048);
    transpose_cast<<<dim3(512 / 32, 2048 / 32), 256, 0, stream>>>(Wk, Wtqkv + (size_t)2048 * D_, D_, 512);
    transpose_cast<<<dim3(512 / 32, 2048 / 32), 256, 0, stream>>>(Wv, Wtqkv + (size_t)2560 * D_, D_, 512);
    transpose_cast<<<dim3(2048 / 32, 2048 / 32), 256, 0, stream>>>(Wo, Wto, 2048, 2048);

    // 2) fused QKV projection (f16 out) — 256² 8-phase, register-resident B
    gemm_mfma256<1><<<dim3(QKVW / 256, L_ / 256), 512, 0, stream>>>(xb, Wtqkv, qkv, L_, QKVW, D_);

    // 3) RMSNorm + RoPE in place (wave-per-row, vectorized, no barriers)
    norm_rope_w<<<(L_ * 12) / 4, 256, 0, stream>>>(qkv, q_scale, k_scale, positions);

    // 4) V transpose to [g][d][L] (into xb region, now dead)
    vt_prep<<<dim3(L_ / 64, KVH_), 256, 0, stream>>>(qkv, vtg);

    // 5) flash MFMA attention v4 (async staged, double-buffered)
    attn_mfma<<<(L_ / 16) * KVH_, 256, 0, stream>>>(qkv, vtg, ao);

    // 6) output projection (fp32 out)
    gemm_mfma<0><<<dim3(D_ / 128, L_ / 128), 256, 0, stream>>>(ao, Wto, out, L_, D_, 2048);
}

// Round 5
// 304.701 us; speedup vs baseline: 1.0142x; 1.0142x over previous
//
#include <hip/hip_runtime.h>
#include <hip/hip_bf16.h>
#include <math.h>
#include <stdint.h>

#define L_      4096
#define D_      2048
#define H_      8
#define KVH_    2
#define HD_     256
#define WINDOW_ 512
#define QKVW    3072   // 2048 q + 512 k + 512 v

typedef __attribute__((ext_vector_type(8))) _Float16 f16x8;
typedef __attribute__((ext_vector_type(4))) _Float16 f16x4;
typedef __attribute__((ext_vector_type(4))) short s16x4;
typedef __attribute__((ext_vector_type(4))) float f32x4;

__device__ __forceinline__ short f2h(float f) {
    _Float16 h = (_Float16)f;           // RNE
    return *reinterpret_cast<short*>(&h);
}
__device__ __forceinline__ float h2f(short s) {
    _Float16 h = *reinterpret_cast<_Float16*>(&s);
    return (float)h;
}

// async global->LDS 16B per lane; lds base must be wave-uniform
__device__ __forceinline__ void gl2lds16(const void* g, void* l) {
    __builtin_amdgcn_global_load_lds(
        (const __attribute__((address_space(1))) uint32_t*)g,
        (__attribute__((address_space(3))) uint32_t*)l, 16, 0, 0);
}

// ---------------------------------------------------------------------------
// cast fp32 -> fp16 (bits in short), 8 elems/thread
// ---------------------------------------------------------------------------
__global__ __launch_bounds__(256) void cast_f16(const float* __restrict__ X,
                                                short* __restrict__ Y, int n) {
    int idx = (blockIdx.x * 256 + threadIdx.x) * 8;
    if (idx >= n) return;
    float4 a = *(const float4*)(X + idx);
    float4 b = *(const float4*)(X + idx + 4);
    s16x4 o0, o1;
    o0[0]=f2h(a.x); o0[1]=f2h(a.y); o0[2]=f2h(a.z); o0[3]=f2h(a.w);
    o1[0]=f2h(b.x); o1[1]=f2h(b.y); o1[2]=f2h(b.z); o1[3]=f2h(b.w);
    *(s16x4*)(Y + idx)     = o0;
    *(s16x4*)(Y + idx + 4) = o1;
}

// ---------------------------------------------------------------------------
// transpose-cast: W fp32 [K][N] -> Wt fp16 [N][K]
// ---------------------------------------------------------------------------
__global__ __launch_bounds__(256) void transpose_cast(const float* __restrict__ W,
                                                      short* __restrict__ Wt,
                                                      int K, int N) {
    __shared__ float tl[32][33];
    int t = threadIdx.x;
    int c = t & 31, r4 = (t >> 5) * 4;
    int k0 = blockIdx.y * 32, n0 = blockIdx.x * 32;
#pragma unroll
    for (int i = 0; i < 4; ++i)
        tl[r4 + i][c] = W[(size_t)(k0 + r4 + i) * N + n0 + c];
    __syncthreads();
#pragma unroll
    for (int i = 0; i < 4; ++i)
        Wt[(size_t)(n0 + r4 + i) * K + k0 + c] = f2h(tl[c][r4 + i]);
}

// ---------------------------------------------------------------------------
// fp16 MFMA GEMM v2: C[M][N] = A[M][K] * Bt[N][K]^T
// 128x128 tile, BK=64 (128B LDS rows), XOR-swizzled chunk placement.
// ---------------------------------------------------------------------------
template <int OUT_HALF>
__global__ __launch_bounds__(256) void gemm_mfma(const short* __restrict__ A,
                                                 const short* __restrict__ Bt,
                                                 void* __restrict__ Cout,
                                                 int M, int N, int K) {
    __shared__ short As[128][64];   // 16 KB each, rows 128B
    __shared__ short Bs[128][64];

    const int tid = threadIdx.x;
    const int w = tid >> 6, lane = tid & 63;
    const int lq = lane & 15, quad = lane >> 4;
    const int bm = blockIdx.y * 128, bn = blockIdx.x * 128;
    const int wm = (w & 1) * 64, wn = (w >> 1) * 64;
    const int lrow = lane >> 3;      // 0..7: row within 8-row staging group
    const int slot = lane & 7;       // 0..7: LDS 16B slot this lane fills

    f32x4 acc[4][4];
#pragma unroll
    for (int i = 0; i < 4; ++i)
#pragma unroll
        for (int j = 0; j < 4; ++j) acc[i][j] = 0;

    for (int k0 = 0; k0 < K; k0 += 64) {
        // stage 128 rows x 128B per matrix; wave stages 8 rows per instr
#pragma unroll
        for (int c = 0; c < 4; ++c) {
            const int r0 = w * 32 + c * 8;            // wave-uniform
            const int row = r0 + lrow;
            const int chunk = slot ^ (row & 7);       // swizzled source chunk
            gl2lds16(A  + (size_t)(bm + row) * K + k0 + chunk * 8, &As[r0][0]);
            gl2lds16(Bt + (size_t)(bn + row) * K + k0 + chunk * 8, &Bs[r0][0]);
        }
        __syncthreads();   // drains vmcnt -> staged data visible

#pragma unroll
        for (int f = 0; f < 2; ++f) {
            const int sA = (((f * 4) + quad) ^ (lq & 7)) * 8;  // un-swizzle
            f16x8 af[4], bfr[4];
#pragma unroll
            for (int i = 0; i < 4; ++i) af[i]  = *(const f16x8*)&As[wm + i * 16 + lq][sA];
#pragma unroll
            for (int j = 0; j < 4; ++j) bfr[j] = *(const f16x8*)&Bs[wn + j * 16 + lq][sA];
#pragma unroll
            for (int i = 0; i < 4; ++i)
#pragma unroll
                for (int j = 0; j < 4; ++j)
                    acc[i][j] = __builtin_amdgcn_mfma_f32_16x16x32_f16(af[i], bfr[j], acc[i][j], 0, 0, 0);
        }
        __syncthreads();
    }

    // epilogue: C/D layout col=lane&15, row=quad*4+reg
#pragma unroll
    for (int i = 0; i < 4; ++i)
#pragma unroll
        for (int r = 0; r < 4; ++r) {
            int row = bm + wm + i * 16 + quad * 4 + r;
#pragma unroll
            for (int j = 0; j < 4; ++j) {
                int col = bn + wn + j * 16 + lq;
                float v = acc[i][j][r];
                if (OUT_HALF) ((short*)Cout)[(size_t)row * N + col] = f2h(v);
                else          ((float*)Cout)[(size_t)row * N + col] = v;
            }
        }
}

// ---------------------------------------------------------------------------
// RMSNorm (+scale) (+RoPE), wave-per-row, no LDS/barriers.
// ---------------------------------------------------------------------------
__global__ __launch_bounds__(256) void norm_rope_w(short* __restrict__ qkv,
                                                   const float* __restrict__ q_scale,
                                                   const float* __restrict__ k_scale,
                                                   const int* __restrict__ positions) {
    const int w = threadIdx.x >> 6, lane = threadIdx.x & 63;
    const int row = blockIdx.x * 4 + w;
    const int token = row / 12, ridx = row % 12;
    short* p = qkv + (size_t)token * QKVW + ridx * HD_ + lane * 4;

    const s16x4 raw = *(const s16x4*)p;
    float xv[4];
#pragma unroll
    for (int i = 0; i < 4; ++i) xv[i] = h2f(raw[i]);
    float ss = xv[0]*xv[0] + xv[1]*xv[1] + xv[2]*xv[2] + xv[3]*xv[3];
#pragma unroll
    for (int off = 32; off > 0; off >>= 1) ss += __shfl_xor(ss, off);
    const float rinv = rsqrtf(ss * (1.0f / (float)HD_) + 1e-6f);
#pragma unroll
    for (int i = 0; i < 4; ++i) xv[i] *= rinv;

    if (ridx < 10) {                                  // q,k: scale + rope
        const float* scp = (ridx < 8 ? q_scale : k_scale) + lane * 4;
        const float4 sc = *(const float4*)scp;
        xv[0] *= sc.x; xv[1] *= sc.y; xv[2] *= sc.z; xv[3] *= sc.w;

        const int pos = positions[token];
        float ov[4];
#pragma unroll
        for (int i = 0; i < 4; ++i) ov[i] = __shfl_xor(xv[i], 32);
        const float sgn = (lane < 32) ? -1.0f : 1.0f;
        const int dbase = (lane & 31) * 4;            // freq index base
#pragma unroll
        for (int i = 0; i < 4; ++i) {
            const float fe = (float)(dbase + i) * (1.0f / 128.0f);
            const float inv_ts = __expf(fe * -9.210340371976184f);   // BASE^-fe
            const float ang = (float)pos * inv_ts;
            float s, c;
            __sincosf(ang, &s, &c);
            xv[i] = xv[i] * c + sgn * ov[i] * s;
        }
    }

    s16x4 o;
#pragma unroll
    for (int i = 0; i < 4; ++i) o[i] = f2h(xv[i]);
    *(s16x4*)p = o;
}

// ---------------------------------------------------------------------------
// V transpose: normalized V from qkv -> Vt_glob[g][d][L] (fp16)
// ---------------------------------------------------------------------------
__global__ __launch_bounds__(256) void vt_prep(const short* __restrict__ qkv,
                                               short* __restrict__ vtg) {
    const int tok0 = blockIdx.x * 64;
    const int g = blockIdx.y;
    const int tid = threadIdx.x;
    __shared__ short Vs[64][264];
#pragma unroll
    for (int i = 0; i < 8; ++i) {
        int f = (tid + i * 256) * 8;
        int tok = f >> 8, d = f & 255;
        *(int4*)&Vs[tok][d] =
            *(const int4*)(qkv + (size_t)(tok0 + tok) * QKVW + 2560 + g * HD_ + d);
    }
    __syncthreads();
    const int d = tid;
    short tmp[64];
#pragma unroll
    for (int j = 0; j < 64; ++j) tmp[j] = Vs[j][d];
    short* dst = vtg + ((size_t)g * HD_ + d) * L_ + tok0;
#pragma unroll
    for (int c = 0; c < 8; ++c)
        *(int4*)(dst + c * 8) = *(const int4*)&tmp[c * 8];
}

// ---------------------------------------------------------------------------
// Flash MFMA attention v5 — 8-wave blocks: 32 queries x kv-group g.
// Waves = 4 heads x 2 query-subtiles sharing one K/V LDS staging ->
// per-CU kt-iterations, barrier events, staging writes and global K/V
// fetch all HALVED vs v4; per-wave compute identical.
// Same S^T layout, global_load_lds staging (swizzled global addr, linear
// LDS), double buffer, counted vmcnt(4), raw s_barrier.
// ---------------------------------------------------------------------------
__global__ __launch_bounds__(512) void attn_mfma(const short* __restrict__ qkv,
                                                 const short* __restrict__ vtg,
                                                 short* __restrict__ ao) {
    const int bx = blockIdx.x;
    const int g = bx & 1, qt = bx >> 1;
    const int qb = qt * 32;                  // block query base (32 queries)
    const int tid = threadIdx.x;
    const int w = tid >> 6, lane = tid & 63;
    const int lq = lane & 15, quad = lane >> 4;
    const int h = g * 4 + (w & 3);           // head for this wave
    const int q0 = qb + (w >> 2) * 16;       // query-subtile base

    // [0,16384): Ks[2][32][256]  [16384,32768): Vt[2][16][512]
    // epilogue overlays [0, 33792): 8 waves x 4224 shorts
    __shared__ short lds[33792];

    // Q B-fragments: B[k=quad*8+j][n=lq] = Q[q0+lq][f*32+quad*8]
    f16x8 qf[8];
    {
        const short* qrow = qkv + (size_t)(q0 + lq) * QKVW + h * HD_;
#pragma unroll
        for (int f = 0; f < 8; ++f)
            qf[f] = *(const f16x8*)(qrow + f * 32 + quad * 8);
    }

    float m_run = -INFINITY, l_run = 0.0f;   // per-lane: query q0+lq

    f32x4 accO[16];                          // O^T[d=dt*16+quad*4+r][q=lq]
#pragma unroll
    for (int dt = 0; dt < 16; ++dt) accO[dt] = 0;

    const short* kcol = qkv + 2048 + g * HD_;
    const short* vrow = vtg + (size_t)g * HD_ * L_;
    const int qi = q0 + lq;

    // staging lane roles (8 waves: 4 loads/lane per tile)
    const int kl5 = lane >> 5;               // K: row within pair
    const int ksl = lane & 31;               // K: 16B slot
    const int vdm = ((lane >> 5) << 3) | (lane & 7);   // V: d within window
    const int vkc = (lane >> 3) & 3;                   // V: 8-key chunk

    auto stageKV = [&](int b, int kb) {
#pragma unroll
        for (int i = 0; i < 2; ++i) {
            const int r0 = w * 4 + 2 * i;                  // wave-uniform
            const int row = r0 + kl5;
            const int cs = ksl ^ (row & 7);                // swizzled src chunk
            const int kj = min(max(kb + row, 0), L_ - 1);  // masked later
            gl2lds16(kcol + (size_t)kj * QKVW + cs * 8, lds + b * 8192 + r0 * 256);
        }
        const int ck = min(max(kb + vkc * 8, 0), L_ - 8);
#pragma unroll
        for (int j = 0; j < 2; ++j) {
            const int wv = w * 2 + j;                      // wave-uniform window
            gl2lds16(vrow + (size_t)(wv * 16 + vdm) * L_ + ck,
                     lds + 16384 + b * 8192 + wv * 512);
        }
    };

    // first kt with any key index >= 0: kbase+32 > 0
    const int kt0 = (qb >= 512) ? 0 : ((480 - qb) / 32 + 1);
    int buf = 0;
    stageKV(0, qb - WINDOW_ + kt0 * 32);

    for (int kt = kt0; kt < 17; ++kt) {
        const int kbase = qb - WINDOW_ + kt * 32;
        if (kt < 16) {
            stageKV(buf ^ 1, kbase + 32);
            asm volatile("s_waitcnt vmcnt(4)" ::: "memory");   // tile kt landed
        } else {
            asm volatile("s_waitcnt vmcnt(0)" ::: "memory");
        }
        __builtin_amdgcn_s_barrier();
        __builtin_amdgcn_sched_barrier(0);

        const short* KsB = lds + buf * 8192;
        const short* VtB = lds + 16384 + buf * 8192;

        // --- S^T = K Q^T : two 16-key subtiles ---
        f32x4 st0 = 0, st1 = 0;
        __builtin_amdgcn_s_setprio(1);
#pragma unroll
        for (int f = 0; f < 8; ++f) {
            const int sl = ((f * 4 + quad) ^ (lq & 7)) * 8;
            f16x8 kf0 = *(const f16x8*)(KsB + lq * 256 + sl);
            f16x8 kf1 = *(const f16x8*)(KsB + (16 + lq) * 256 + sl);
            st0 = __builtin_amdgcn_mfma_f32_16x16x32_f16(kf0, qf[f], st0, 0, 0, 0);
            st1 = __builtin_amdgcn_mfma_f32_16x16x32_f16(kf1, qf[f], st1, 0, 0, 0);
        }
        __builtin_amdgcn_s_setprio(0);

        // --- register softmax (keys on (quad,r), query = lq) ---
        const int kA = kbase + quad * 4;
        const int kB = kA + 16;
        float sv[8]; bool vd[8];
#pragma unroll
        for (int r = 0; r < 4; ++r) {
            int ka = kA + r, kb2 = kB + r;
            vd[r]     = (ka >= 0) && (ka <= qi) && (ka > qi - WINDOW_);
            vd[4 + r] = (kb2 >= 0) && (kb2 <= qi) && (kb2 > qi - WINDOW_);
            sv[r]     = vd[r]     ? st0[r] : -INFINITY;
            sv[4 + r] = vd[4 + r] ? st1[r] : -INFINITY;
        }
        float mt = sv[0];
#pragma unroll
        for (int i = 1; i < 8; ++i) mt = fmaxf(mt, sv[i]);
        mt = fmaxf(mt, __shfl_xor(mt, 16));
        mt = fmaxf(mt, __shfl_xor(mt, 32));
        const float mn = fmaxf(m_run, mt);
        const float alpha = (mn == -INFINITY) ? 1.0f : __expf(m_run - mn);
        float pv[8], rs = 0.0f;
#pragma unroll
        for (int i = 0; i < 8; ++i) {
            pv[i] = vd[i] ? __expf(sv[i] - mn) : 0.0f;
            rs += pv[i];
        }
        rs += __shfl_xor(rs, 16);
        rs += __shfl_xor(rs, 32);
        m_run = mn;
        l_run = l_run * alpha + rs;

        // P^T B-frags (B[k=quad*4+i][n=lq]) straight from registers
        f16x4 p0, p1;
#pragma unroll
        for (int i = 0; i < 4; ++i) { p0[i] = (_Float16)pv[i]; p1[i] = (_Float16)pv[4 + i]; }

        // --- PV: O^T[d][q] += V^T[d][k] P^T[k][q], 16x16x16 MFMAs ---
        const int sl0 = ((lq >> 3) << 5) | ((quad >> 1) << 3) | (lq & 7);
        const int hh = (quad & 1) * 4;
        __builtin_amdgcn_s_setprio(1);
#pragma unroll
        for (int dt = 0; dt < 16; ++dt) {
            f16x4 v0 = *(const f16x4*)(VtB + dt * 512 + sl0 * 8 + hh);
            f16x4 v1 = *(const f16x4*)(VtB + dt * 512 + (sl0 | 16) * 8 + hh);
            f32x4 t = accO[dt];
#pragma unroll
            for (int r = 0; r < 4; ++r) t[r] *= alpha;
            t = __builtin_amdgcn_mfma_f32_16x16x16f16(v0, p0, t, 0, 0, 0);
            t = __builtin_amdgcn_mfma_f32_16x16x16f16(v1, p1, t, 0, 0, 0);
            accO[dt] = t;
        }
        __builtin_amdgcn_s_setprio(0);

        __builtin_amdgcn_s_barrier();     // all reads of buf done before restage
        __builtin_amdgcn_sched_barrier(0);
        buf ^= 1;
    }

    // --- epilogue: untranspose O^T via per-wave LDS region, then coalesced store
    const float inv = 1.0f / l_run;            // per-query (lane) scalar
    short* myE = lds + w * 4224;               // 16 rows x 264 shorts per wave
#pragma unroll
    for (int dt = 0; dt < 16; ++dt) {
        f16x4 e;
#pragma unroll
        for (int r = 0; r < 4; ++r) e[r] = (_Float16)(accO[dt][r] * inv);
        *(f16x4*)&myE[lq * 264 + dt * 16 + quad * 4] = e;   // O[q=lq][d]
    }
    // same-wave read-back (lgkmcnt only), coalesced global store
    {
        const int row = lane >> 2;             // 16 q rows
        const int c0 = (lane & 3) * 64;        // 4 x 64-short segments
        short* orow = ao + (size_t)(q0 + row) * 2048 + h * HD_ + c0;
#pragma unroll
        for (int u = 0; u < 8; ++u)
            *(int4*)(orow + u * 8) = *(const int4*)&myE[row * 264 + c0 + u * 8];
    }
}

// ---------------------------------------------------------------------------
extern "C" void kernel_launch(void* const* d_in, const int* in_sizes, int n_in,
                              void* d_out, int out_size, void* d_ws, size_t ws_size,
                              hipStream_t stream) {
    const float* x         = (const float*)d_in[0];
    const int*   positions = (const int*)d_in[1];
    const float* Wq        = (const float*)d_in[2];
    const float* Wk        = (const float*)d_in[3];
    const float* Wv        = (const float*)d_in[4];
    const float* Wo        = (const float*)d_in[5];
    const float* q_scale   = (const float*)d_in[6];
    const float* k_scale   = (const float*)d_in[7];
    float*       out       = (float*)d_out;

    // workspace layout (bytes, ~80 MB total)
    char* ws = (char*)d_ws;
    short* xb    = (short*)(ws);                 // [4096][2048] f16   16 MB
    short* qkv   = (short*)(ws + 16777216);      // [4096][3072] f16   24 MB
    short* ao    = (short*)(ws + 41943040);      // [4096][2048] f16   16 MB
    short* Wtqkv = (short*)(ws + 58720256);      // [3072][2048] f16   12 MB
    short* Wto   = (short*)(ws + 71303168);      // [2048][2048] f16    8 MB
    short* vtg   = xb;                           // aliases xb (dead after QKV GEMM)

    // 1) casts + weight transposes
    cast_f16<<<4096, 256, 0, stream>>>(x, xb, L_ * D_);
    transpose_cast<<<dim3(2048 / 32, 2048 / 32), 256, 0, stream>>>(Wq, Wtqkv, D_, 2048);
    transpose_cast<<<dim3(512 / 32, 2048 / 32), 256, 0, stream>>>(Wk, Wtqkv + (size_t)2048 * D_, D_, 512);
    transpose_cast<<<dim3(512 / 32, 2048 / 32), 256, 0, stream>>>(Wv, Wtqkv + (size_t)2560 * D_, D_, 512);
    transpose_cast<<<dim3(2048 / 32, 2048 / 32), 256, 0, stream>>>(Wo, Wto, 2048, 2048);

    // 2) fused QKV projection (f16 out) — v2 128² (proven 65.5 µs)
    gemm_mfma<1><<<dim3(QKVW / 128, L_ / 128), 256, 0, stream>>>(xb, Wtqkv, qkv, L_, QKVW, D_);

    // 3) RMSNorm + RoPE in place (wave-per-row, vectorized, no barriers)
    norm_rope_w<<<(L_ * 12) / 4, 256, 0, stream>>>(qkv, q_scale, k_scale, positions);

    // 4) V transpose to [g][d][L] (into xb region, now dead)
    vt_prep<<<dim3(L_ / 64, KVH_), 256, 0, stream>>>(qkv, vtg);

    // 5) flash MFMA attention v5 (8-wave, 32 queries/block, shared K/V staging)
    attn_mfma<<<(L_ / 32) * KVH_, 512, 0, stream>>>(qkv, vtg, ao);

    // 6) output projection (fp32 out)
    gemm_mfma<0><<<dim3(D_ / 128, L_ / 128), 256, 0, stream>>>(ao, Wto, out, L_, D_, 2048);
}

// Round 6
// 295.771 us; speedup vs baseline: 1.0448x; 1.0302x over previous
//
#include <hip/hip_runtime.h>
#include <hip/hip_bf16.h>
#include <math.h>
#include <stdint.h>

#define L_      4096
#define D_      2048
#define H_      8
#define KVH_    2
#define HD_     256
#define WINDOW_ 512
#define QKVW    3072   // 2048 q + 512 k + 512 v

typedef __attribute__((ext_vector_type(8))) _Float16 f16x8;
typedef __attribute__((ext_vector_type(4))) _Float16 f16x4;
typedef __attribute__((ext_vector_type(4))) short s16x4;
typedef __attribute__((ext_vector_type(4))) float f32x4;

__device__ __forceinline__ short f2h(float f) {
    _Float16 h = (_Float16)f;           // RNE
    return *reinterpret_cast<short*>(&h);
}
__device__ __forceinline__ float h2f(short s) {
    _Float16 h = *reinterpret_cast<_Float16*>(&s);
    return (float)h;
}

// async global->LDS 16B per lane; lds base must be wave-uniform
__device__ __forceinline__ void gl2lds16(const void* g, void* l) {
    __builtin_amdgcn_global_load_lds(
        (const __attribute__((address_space(1))) uint32_t*)g,
        (__attribute__((address_space(3))) uint32_t*)l, 16, 0, 0);
}

// ---------------------------------------------------------------------------
// prep_fused: one launch for x-cast + all 4 weight transpose-casts.
// blocks [0,4096): cast x fp32->fp16
// [4096,8192): Wq^T  [8192,9216): Wk^T  [9216,10240): Wv^T  [10240,14336): Wo^T
// ---------------------------------------------------------------------------
__global__ __launch_bounds__(256) void prep_fused(const float* __restrict__ x,
                                                  short* __restrict__ xb,
                                                  const float* __restrict__ Wq,
                                                  const float* __restrict__ Wk,
                                                  const float* __restrict__ Wv,
                                                  const float* __restrict__ Wo,
                                                  short* __restrict__ Wtqkv,
                                                  short* __restrict__ Wto) {
    __shared__ float tl[32][33];
    const int bid = blockIdx.x;
    const int t = threadIdx.x;

    if (bid < 4096) {                       // ---- cast region ----
        int idx = (bid * 256 + t) * 8;
        float4 a = *(const float4*)(x + idx);
        float4 b = *(const float4*)(x + idx + 4);
        s16x4 o0, o1;
        o0[0]=f2h(a.x); o0[1]=f2h(a.y); o0[2]=f2h(a.z); o0[3]=f2h(a.w);
        o1[0]=f2h(b.x); o1[1]=f2h(b.y); o1[2]=f2h(b.z); o1[3]=f2h(b.w);
        *(s16x4*)(xb + idx)     = o0;
        *(s16x4*)(xb + idx + 4) = o1;
        return;
    }

    // ---- transpose regions: W fp32 [2048][N] -> Wt fp16 [N][2048] ----
    const float* W; short* Wt; int N; int rb;
    if (bid < 8192)       { W = Wq; Wt = Wtqkv;                       N = 2048; rb = bid - 4096; }
    else if (bid < 9216)  { W = Wk; Wt = Wtqkv + (size_t)2048 * D_;   N = 512;  rb = bid - 8192; }
    else if (bid < 10240) { W = Wv; Wt = Wtqkv + (size_t)2560 * D_;   N = 512;  rb = bid - 9216; }
    else                  { W = Wo; Wt = Wto;                         N = 2048; rb = bid - 10240; }
    const int K = 2048;
    const int nb = N >> 5;
    const int n0 = (rb % nb) * 32, k0 = (rb / nb) * 32;
    const int c = t & 31, r4 = (t >> 5) * 4;
#pragma unroll
    for (int i = 0; i < 4; ++i)
        tl[r4 + i][c] = W[(size_t)(k0 + r4 + i) * N + n0 + c];
    __syncthreads();
#pragma unroll
    for (int i = 0; i < 4; ++i)
        Wt[(size_t)(n0 + r4 + i) * K + k0 + c] = f2h(tl[c][r4 + i]);
}

// ---------------------------------------------------------------------------
// fp16 MFMA GEMM v2: C[M][N] = A[M][K] * Bt[N][K]^T
// 128x128 tile, BK=64 (128B LDS rows), XOR-swizzled chunk placement.
// ---------------------------------------------------------------------------
template <int OUT_HALF>
__global__ __launch_bounds__(256) void gemm_mfma(const short* __restrict__ A,
                                                 const short* __restrict__ Bt,
                                                 void* __restrict__ Cout,
                                                 int M, int N, int K) {
    __shared__ short As[128][64];   // 16 KB each, rows 128B
    __shared__ short Bs[128][64];

    const int tid = threadIdx.x;
    const int w = tid >> 6, lane = tid & 63;
    const int lq = lane & 15, quad = lane >> 4;
    const int bm = blockIdx.y * 128, bn = blockIdx.x * 128;
    const int wm = (w & 1) * 64, wn = (w >> 1) * 64;
    const int lrow = lane >> 3;      // 0..7: row within 8-row staging group
    const int slot = lane & 7;       // 0..7: LDS 16B slot this lane fills

    f32x4 acc[4][4];
#pragma unroll
    for (int i = 0; i < 4; ++i)
#pragma unroll
        for (int j = 0; j < 4; ++j) acc[i][j] = 0;

    for (int k0 = 0; k0 < K; k0 += 64) {
        // stage 128 rows x 128B per matrix; wave stages 8 rows per instr
#pragma unroll
        for (int c = 0; c < 4; ++c) {
            const int r0 = w * 32 + c * 8;            // wave-uniform
            const int row = r0 + lrow;
            const int chunk = slot ^ (row & 7);       // swizzled source chunk
            gl2lds16(A  + (size_t)(bm + row) * K + k0 + chunk * 8, &As[r0][0]);
            gl2lds16(Bt + (size_t)(bn + row) * K + k0 + chunk * 8, &Bs[r0][0]);
        }
        __syncthreads();   // drains vmcnt -> staged data visible

#pragma unroll
        for (int f = 0; f < 2; ++f) {
            const int sA = (((f * 4) + quad) ^ (lq & 7)) * 8;  // un-swizzle
            f16x8 af[4], bfr[4];
#pragma unroll
            for (int i = 0; i < 4; ++i) af[i]  = *(const f16x8*)&As[wm + i * 16 + lq][sA];
#pragma unroll
            for (int j = 0; j < 4; ++j) bfr[j] = *(const f16x8*)&Bs[wn + j * 16 + lq][sA];
#pragma unroll
            for (int i = 0; i < 4; ++i)
#pragma unroll
                for (int j = 0; j < 4; ++j)
                    acc[i][j] = __builtin_amdgcn_mfma_f32_16x16x32_f16(af[i], bfr[j], acc[i][j], 0, 0, 0);
        }
        __syncthreads();
    }

    // epilogue: C/D layout col=lane&15, row=quad*4+reg
#pragma unroll
    for (int i = 0; i < 4; ++i)
#pragma unroll
        for (int r = 0; r < 4; ++r) {
            int row = bm + wm + i * 16 + quad * 4 + r;
#pragma unroll
            for (int j = 0; j < 4; ++j) {
                int col = bn + wn + j * 16 + lq;
                float v = acc[i][j][r];
                if (OUT_HALF) ((short*)Cout)[(size_t)row * N + col] = f2h(v);
                else          ((float*)Cout)[(size_t)row * N + col] = v;
            }
        }
}

// ---------------------------------------------------------------------------
// normvt_fused: one launch for {q,k RMSNorm+scale+RoPE} and {v RMSNorm +
// transpose to vtg}. The two regions are independent (attention reads V
// only through vtg), so they share a launch.
// blocks [0,10240): q,k rows (4 rows/block, wave-per-row)
// blocks [10240,10368): v tiles (64 tokens x group g), norm fused into
//                       the transpose (saves a full V read+write pass)
// ---------------------------------------------------------------------------
__global__ __launch_bounds__(256) void normvt_fused(short* __restrict__ qkv,
                                                    const float* __restrict__ q_scale,
                                                    const float* __restrict__ k_scale,
                                                    const int* __restrict__ positions,
                                                    short* __restrict__ vtg) {
    __shared__ short Vs[64][264];
    __shared__ float ri[64];
    const int bid = blockIdx.x;
    const int tid = threadIdx.x;

    if (bid < 10240) {                 // ---- q,k norm + rope ----
        const int w = tid >> 6, lane = tid & 63;
        const int r = bid * 4 + w;
        const int token = r / 10, ridx = r % 10;
        short* p = qkv + (size_t)token * QKVW + ridx * HD_ + lane * 4;

        const s16x4 raw = *(const s16x4*)p;
        float xv[4];
#pragma unroll
        for (int i = 0; i < 4; ++i) xv[i] = h2f(raw[i]);
        float ss = xv[0]*xv[0] + xv[1]*xv[1] + xv[2]*xv[2] + xv[3]*xv[3];
#pragma unroll
        for (int off = 32; off > 0; off >>= 1) ss += __shfl_xor(ss, off);
        const float rinv = rsqrtf(ss * (1.0f / (float)HD_) + 1e-6f);
        const float* scp = (ridx < 8 ? q_scale : k_scale) + lane * 4;
        const float4 sc = *(const float4*)scp;
        xv[0] *= rinv * sc.x; xv[1] *= rinv * sc.y;
        xv[2] *= rinv * sc.z; xv[3] *= rinv * sc.w;

        const int pos = positions[token];
        float ov[4];
#pragma unroll
        for (int i = 0; i < 4; ++i) ov[i] = __shfl_xor(xv[i], 32);
        const float sgn = (lane < 32) ? -1.0f : 1.0f;
        const int dbase = (lane & 31) * 4;            // freq index base
#pragma unroll
        for (int i = 0; i < 4; ++i) {
            const float fe = (float)(dbase + i) * (1.0f / 128.0f);
            const float inv_ts = __expf(fe * -9.210340371976184f);   // BASE^-fe
            const float ang = (float)pos * inv_ts;
            float s, c;
            __sincosf(ang, &s, &c);
            xv[i] = xv[i] * c + sgn * ov[i] * s;
        }
        s16x4 o;
#pragma unroll
        for (int i = 0; i < 4; ++i) o[i] = f2h(xv[i]);
        *(s16x4*)p = o;
        return;
    }

    // ---- v: RMSNorm + transpose to vtg[g][d][L] ----
    const int rb = bid - 10240;
    const int tok0 = (rb >> 1) * 64;
    const int g = rb & 1;
#pragma unroll
    for (int i = 0; i < 8; ++i) {
        int f = (tid + i * 256) * 8;
        int tok = f >> 8, d = f & 255;
        *(int4*)&Vs[tok][d] =
            *(const int4*)(qkv + (size_t)(tok0 + tok) * QKVW + 2560 + g * HD_ + d);
    }
    __syncthreads();
    {
        const int t = tid >> 2, s = tid & 3;          // 4 lanes per token
        float ss = 0.0f;
#pragma unroll
        for (int d2 = 0; d2 < 16; ++d2) {
            s16x4 v4 = *(const s16x4*)&Vs[t][s * 64 + d2 * 4];
#pragma unroll
            for (int k2 = 0; k2 < 4; ++k2) { float val = h2f(v4[k2]); ss += val * val; }
        }
        ss += __shfl_xor(ss, 1);
        ss += __shfl_xor(ss, 2);
        if (s == 0) ri[t] = rsqrtf(ss * (1.0f / (float)HD_) + 1e-6f);
    }
    __syncthreads();
    const int d = tid;
    short tmp[64];
#pragma unroll
    for (int j = 0; j < 64; ++j) tmp[j] = f2h(h2f(Vs[j][d]) * ri[j]);
    short* dst = vtg + ((size_t)g * HD_ + d) * L_ + tok0;
#pragma unroll
    for (int c = 0; c < 8; ++c)
        *(int4*)(dst + c * 8) = *(const int4*)&tmp[c * 8];
}

// ---------------------------------------------------------------------------
// Flash MFMA attention v4+T13 — S^T layout, global_load_lds staging, double
// buffer, counted vmcnt(8), raw s_barrier, defer-max rescale (THR=8).
// ---------------------------------------------------------------------------
__global__ __launch_bounds__(256) void attn_mfma(const short* __restrict__ qkv,
                                                 const short* __restrict__ vtg,
                                                 short* __restrict__ ao) {
    const int bx = blockIdx.x;
    const int g = bx & 1, qt = bx >> 1;
    const int q0 = qt * 16;
    const int tid = threadIdx.x;
    const int w = tid >> 6, lane = tid & 63;
    const int lq = lane & 15, quad = lane >> 4;
    const int h = g * 4 + w;

    // [0,16384): Ks[2][32][256]  [16384,32768): Vt[2][16][512]
    __shared__ short lds[32768];   // 64 KiB

    f16x8 qf[8];
    {
        const short* qrow = qkv + (size_t)(q0 + lq) * QKVW + h * HD_;
#pragma unroll
        for (int f = 0; f < 8; ++f)
            qf[f] = *(const f16x8*)(qrow + f * 32 + quad * 8);
    }

    float m_run = -INFINITY, l_run = 0.0f;   // per-lane: query q0+lq

    f32x4 accO[16];                          // O^T[d=dt*16+quad*4+r][q=lq]
#pragma unroll
    for (int dt = 0; dt < 16; ++dt) accO[dt] = 0;

    const short* kcol = qkv + 2048 + g * HD_;
    const short* vrow = vtg + (size_t)g * HD_ * L_;
    const int qi = q0 + lq;

    const int kl5 = lane >> 5;               // K: row within pair
    const int ksl = lane & 31;               // K: 16B slot
    const int vdm = ((lane >> 5) << 3) | (lane & 7);   // V: d within window
    const int vkc = (lane >> 3) & 3;                   // V: 8-key chunk

    auto stageKV = [&](int b, int kb) {
#pragma unroll
        for (int i = 0; i < 4; ++i) {
            const int r0 = w * 8 + 2 * i;                  // wave-uniform
            const int row = r0 + kl5;
            const int cs = ksl ^ (row & 7);                // swizzled src chunk
            const int kj = min(max(kb + row, 0), L_ - 1);  // masked later
            gl2lds16(kcol + (size_t)kj * QKVW + cs * 8, lds + b * 8192 + r0 * 256);
        }
        const int ck = min(max(kb + vkc * 8, 0), L_ - 8);
#pragma unroll
        for (int j = 0; j < 4; ++j) {
            const int wv = w * 4 + j;                      // wave-uniform
            gl2lds16(vrow + (size_t)(wv * 16 + vdm) * L_ + ck,
                     lds + 16384 + b * 8192 + wv * 512);
        }
    };

    const int kt0 = (q0 >= 480) ? 0 : ((480 - q0) / 32 + 1);
    int buf = 0;
    stageKV(0, q0 - WINDOW_ + kt0 * 32);

    for (int kt = kt0; kt < 17; ++kt) {
        const int kbase = q0 - WINDOW_ + kt * 32;
        if (kt < 16) {
            stageKV(buf ^ 1, kbase + 32);
            asm volatile("s_waitcnt vmcnt(8)" ::: "memory");   // tile kt landed
        } else {
            asm volatile("s_waitcnt vmcnt(0)" ::: "memory");
        }
        __builtin_amdgcn_s_barrier();
        __builtin_amdgcn_sched_barrier(0);

        const short* KsB = lds + buf * 8192;
        const short* VtB = lds + 16384 + buf * 8192;

        // --- S^T = K Q^T : two 16-key subtiles ---
        f32x4 st0 = 0, st1 = 0;
        __builtin_amdgcn_s_setprio(1);
#pragma unroll
        for (int f = 0; f < 8; ++f) {
            const int sl = ((f * 4 + quad) ^ (lq & 7)) * 8;
            f16x8 kf0 = *(const f16x8*)(KsB + lq * 256 + sl);
            f16x8 kf1 = *(const f16x8*)(KsB + (16 + lq) * 256 + sl);
            st0 = __builtin_amdgcn_mfma_f32_16x16x32_f16(kf0, qf[f], st0, 0, 0, 0);
            st1 = __builtin_amdgcn_mfma_f32_16x16x32_f16(kf1, qf[f], st1, 0, 0, 0);
        }
        __builtin_amdgcn_s_setprio(0);

        // --- register softmax (keys on (quad,r), query = lq) ---
        const int kA = kbase + quad * 4;
        const int kB = kA + 16;
        float sv[8]; bool vd[8];
#pragma unroll
        for (int r = 0; r < 4; ++r) {
            int ka = kA + r, kb2 = kB + r;
            vd[r]     = (ka >= 0) && (ka <= qi) && (ka > qi - WINDOW_);
            vd[4 + r] = (kb2 >= 0) && (kb2 <= qi) && (kb2 > qi - WINDOW_);
            sv[r]     = vd[r]     ? st0[r] : -INFINITY;
            sv[4 + r] = vd[4 + r] ? st1[r] : -INFINITY;
        }
        float mt = sv[0];
#pragma unroll
        for (int i = 1; i < 8; ++i) mt = fmaxf(mt, sv[i]);
        mt = fmaxf(mt, __shfl_xor(mt, 16));
        mt = fmaxf(mt, __shfl_xor(mt, 32));

        // defer-max (T13): only rescale when the wave's max grew past THR=8
        if (!__all(mt <= m_run + 8.0f)) {
            const float mn = fmaxf(m_run, mt);
            const float alpha = (mn == -INFINITY) ? 1.0f : __expf(m_run - mn);
            m_run = mn;
            l_run *= alpha;
#pragma unroll
            for (int dt = 0; dt < 16; ++dt)
#pragma unroll
                for (int r = 0; r < 4; ++r) accO[dt][r] *= alpha;
        }

        float pv[8], rs = 0.0f;
#pragma unroll
        for (int i = 0; i < 8; ++i) {
            pv[i] = vd[i] ? __expf(sv[i] - m_run) : 0.0f;
            rs += pv[i];
        }
        rs += __shfl_xor(rs, 16);
        rs += __shfl_xor(rs, 32);
        l_run += rs;

        // P^T B-frags (B[k=quad*4+i][n=lq]) straight from registers
        f16x4 p0, p1;
#pragma unroll
        for (int i = 0; i < 4; ++i) { p0[i] = (_Float16)pv[i]; p1[i] = (_Float16)pv[4 + i]; }

        // --- PV: O^T[d][q] += V^T[d][k] P^T[k][q], 16x16x16 MFMAs ---
        const int sl0 = ((lq >> 3) << 5) | ((quad >> 1) << 3) | (lq & 7);
        const int hh = (quad & 1) * 4;
        __builtin_amdgcn_s_setprio(1);
#pragma unroll
        for (int dt = 0; dt < 16; ++dt) {
            f16x4 v0 = *(const f16x4*)(VtB + dt * 512 + sl0 * 8 + hh);
            f16x4 v1 = *(const f16x4*)(VtB + dt * 512 + (sl0 | 16) * 8 + hh);
            f32x4 t = accO[dt];
            t = __builtin_amdgcn_mfma_f32_16x16x16f16(v0, p0, t, 0, 0, 0);
            t = __builtin_amdgcn_mfma_f32_16x16x16f16(v1, p1, t, 0, 0, 0);
            accO[dt] = t;
        }
        __builtin_amdgcn_s_setprio(0);

        __builtin_amdgcn_s_barrier();     // all reads of buf done before restage
        __builtin_amdgcn_sched_barrier(0);
        buf ^= 1;
    }

    // --- epilogue: untranspose O^T via per-wave LDS region, then coalesced store
    const float inv = 1.0f / l_run;            // per-query (lane) scalar
    short* myE = lds + w * 4224;               // 16 rows x 264 shorts per wave
#pragma unroll
    for (int dt = 0; dt < 16; ++dt) {
        f16x4 e;
#pragma unroll
        for (int r = 0; r < 4; ++r) e[r] = (_Float16)(accO[dt][r] * inv);
        *(f16x4*)&myE[lq * 264 + dt * 16 + quad * 4] = e;   // O[q=lq][d]
    }
    // same-wave read-back (lgkmcnt only), coalesced global store
    {
        const int row = lane >> 2;             // 16 q rows
        const int c0 = (lane & 3) * 64;        // 4 x 64-short segments
        short* orow = ao + (size_t)(q0 + row) * 2048 + h * HD_ + c0;
#pragma unroll
        for (int u = 0; u < 8; ++u)
            *(int4*)(orow + u * 8) = *(const int4*)&myE[row * 264 + c0 + u * 8];
    }
}

// ---------------------------------------------------------------------------
extern "C" void kernel_launch(void* const* d_in, const int* in_sizes, int n_in,
                              void* d_out, int out_size, void* d_ws, size_t ws_size,
                              hipStream_t stream) {
    const float* x         = (const float*)d_in[0];
    const int*   positions = (const int*)d_in[1];
    const float* Wq        = (const float*)d_in[2];
    const float* Wk        = (const float*)d_in[3];
    const float* Wv        = (const float*)d_in[4];
    const float* Wo        = (const float*)d_in[5];
    const float* q_scale   = (const float*)d_in[6];
    const float* k_scale   = (const float*)d_in[7];
    float*       out       = (float*)d_out;

    // workspace layout (bytes, ~80 MB total)
    char* ws = (char*)d_ws;
    short* xb    = (short*)(ws);                 // [4096][2048] f16   16 MB
    short* qkv   = (short*)(ws + 16777216);      // [4096][3072] f16   24 MB
    short* ao    = (short*)(ws + 41943040);      // [4096][2048] f16   16 MB
    short* Wtqkv = (short*)(ws + 58720256);      // [3072][2048] f16   12 MB
    short* Wto   = (short*)(ws + 71303168);      // [2048][2048] f16    8 MB
    short* vtg   = xb;                           // aliases xb (dead after QKV GEMM)

    // 1) fused cast + weight transposes (one launch)
    prep_fused<<<14336, 256, 0, stream>>>(x, xb, Wq, Wk, Wv, Wo, Wtqkv, Wto);

    // 2) fused QKV projection (f16 out)
    gemm_mfma<1><<<dim3(QKVW / 128, L_ / 128), 256, 0, stream>>>(xb, Wtqkv, qkv, L_, QKVW, D_);

    // 3) fused {q,k norm+rope} + {v norm + transpose} (one launch)
    normvt_fused<<<10368, 256, 0, stream>>>(qkv, q_scale, k_scale, positions, vtg);

    // 4) flash MFMA attention v4 + defer-max
    attn_mfma<<<(L_ / 16) * KVH_, 256, 0, stream>>>(qkv, vtg, ao);

    // 5) output projection (fp32 out)
    gemm_mfma<0><<<dim3(D_ / 128, L_ / 128), 256, 0, stream>>>(ao, Wto, out, L_, D_, 2048);
}